// Round 3
// baseline (193.818 us; speedup 1.0000x reference)
//
#include <hip/hip_runtime.h>
#include <hip/hip_bf16.h>
#include <math.h>

using bf16 = __hip_bfloat16;
typedef short short8 __attribute__((ext_vector_type(8)));   // 8 bf16 = 4 VGPRs
typedef float f32x4 __attribute__((ext_vector_type(4)));    // MFMA 16x16 acc

#define MFMA16 __builtin_amdgcn_mfma_f32_16x16x32_bf16
#define S_ 8192

// swizzled LDS addressing: 128x128 bf16 tile, 256B rows of 16 x 16B chunks.
__device__ __forceinline__ int sw(int r, int chunk) {
  return r * 256 + (((chunk) ^ (r & 15)) << 4);
}

__device__ __forceinline__ float gelu_exact(float y) {
  return 0.5f * y * (1.0f + erff(y * 0.70710678118654752f));
}

__device__ __forceinline__ unsigned pack2(float a, float b) {
  unsigned ra = (unsigned)__bfloat16_as_ushort(__float2bfloat16(a));
  unsigned rb = (unsigned)__bfloat16_as_ushort(__float2bfloat16(b));
  return ra | (rb << 16);
}

// ---- weight transpose+convert: Wt[m][n][k] = bf16(W[m][k][n]); 16 blocks ----
__global__ void transw(const float* __restrict__ wq, const float* __restrict__ wk,
                       const float* __restrict__ wv, const float* __restrict__ wo,
                       bf16* __restrict__ wt) {
  __shared__ bf16 s[32 * 136];              // 32 out-rows x 128 k, pad 8
  int m = blockIdx.x >> 2, sl = blockIdx.x & 3;
  const float* W = (m == 0) ? wq : (m == 1) ? wk : (m == 2) ? wv : wo;
  for (int i = 0; i < 16; ++i) {
    int idx = threadIdx.x + i * 256;        // 0..4095
    int k = idx >> 5, nl = idx & 31;
    s[nl * 136 + k] = __float2bfloat16(W[k * 128 + sl * 32 + nl]);
  }
  __syncthreads();
  for (int i = 0; i < 2; ++i) {
    int c = threadIdx.x + i * 256;          // 0..511
    int nl = c >> 4, ch = c & 15;
    *(uint4*)(wt + m * 16384 + (sl * 32 + nl) * 128 + ch * 8) =
        *(const uint4*)(s + nl * 136 + ch * 8);
  }
}

// ---- mm helpers: 16-row strip, acc[8] --------------------------------------
__device__ __forceinline__ void clr8(f32x4 acc[8]) {
#pragma unroll
  for (int j = 0; j < 8; ++j) acc[j] = (f32x4){0.f, 0.f, 0.f, 0.f};
}

// A = own strip (LDS swizzled), B = global pre-transposed weight [n][k]
__device__ __forceinline__ void mm_g(const char* tA, const char* wB, int row0,
                                     int l15, int quad, f32x4 acc[8]) {
#pragma unroll
  for (int t = 0; t < 4; ++t) {
    short8 a = *(const short8*)(tA + sw(row0 + l15, 4 * t + quad));
#pragma unroll
    for (int ct = 0; ct < 8; ++ct) {
      short8 bb = *(const short8*)(wB + (ct * 16 + l15) * 256 + t * 64 + quad * 16);
      acc[ct] = MFMA16(a, bb, acc[ct], 0, 0, 0);
    }
  }
}

// A = own strip (LDS), B = LDS tile stored [n][k] swizzled
__device__ __forceinline__ void mm_l(const char* tA, const char* tB, int row0,
                                     int l15, int quad, f32x4 acc[8]) {
#pragma unroll
  for (int t = 0; t < 4; ++t) {
    short8 a = *(const short8*)(tA + sw(row0 + l15, 4 * t + quad));
#pragma unroll
    for (int ct = 0; ct < 8; ++ct) {
      short8 bb = *(const short8*)(tB + sw(ct * 16 + l15, 4 * t + quad));
      acc[ct] = MFMA16(a, bb, acc[ct], 0, 0, 0);
    }
  }
}

// C/D strip -> row-major swizzled tile (own 16 rows), optional per-row scale
__device__ __forceinline__ void store_strip(char* tile, int row0, int l15, int quad,
                                            const f32x4 acc[8], const float* rs) {
#pragma unroll
  for (int ct = 0; ct < 8; ++ct) {
    int col = ct * 16 + l15;
#pragma unroll
    for (int r = 0; r < 4; ++r) {
      int row = row0 + quad * 4 + r;
      float v = acc[ct][r];
      if (rs) v *= rs[r];
      *(bf16*)(tile + sw(row, col >> 3) + (col & 7) * 2) = __float2bfloat16(v);
    }
  }
}

// C/D strip -> transposed tile [col][row], packed ds_write_b64
__device__ __forceinline__ void storeT_strip(char* tile, int row0, int l15, int quad,
                                             const f32x4 acc[8]) {
  int seq = row0 + quad * 4;                // 4-aligned
#pragma unroll
  for (int ct = 0; ct < 8; ++ct) {
    int d = ct * 16 + l15;
    unsigned p[2] = {pack2(acc[ct][0], acc[ct][1]), pack2(acc[ct][2], acc[ct][3])};
    *(uint2*)(tile + sw(d, seq >> 3) + (seq & 7) * 2) = *(const uint2*)p;
  }
}

// ---- main: per-block attention + LN + GELU + second-half fill ---------------
__global__ __launch_bounds__(512, 4) void attn_ln_gelu(
    const float* __restrict__ x, const bf16* __restrict__ wt,
    const float* __restrict__ gamma, const float* __restrict__ beta,
    float* __restrict__ out) {
  __shared__ uint4 ldsbuf[4096];            // 64 KB: 2 tiles
  char* t_x = (char*)ldsbuf;                // Xb -> Q -> P -> O (own strips)
  char* t_k = t_x + 32768;                  // K -> V^T

  const int tid = threadIdx.x;
  const int wave = tid >> 6, lane = tid & 63;
  const int l15 = lane & 15, quad = lane >> 4;
  const int row0 = wave << 4;               // own 16-row strip
  const int b = blockIdx.x >> 6, blk = blockIdx.x & 63;
  const float* xb = x + ((size_t)b * S_ + (size_t)blk * 128) * 128;
  float* outb = out + ((size_t)b * 2 * S_ + (size_t)blk * 128) * 128;

  // ---- second-half fill: out2 = gelu(beta[d]) broadcast (independent work,
  // issued first so the stores drain under the compute)
  {
    float* o2 = out + ((size_t)b * 2 * S_ + (size_t)(S_ + blk * 128)) * 128;
    int c0 = (tid * 4) & 127;
    float4 bv = *(const float4*)(beta + c0);
    float4 gv;
    gv.x = gelu_exact(bv.x); gv.y = gelu_exact(bv.y);
    gv.z = gelu_exact(bv.z); gv.w = gelu_exact(bv.w);
#pragma unroll
    for (int j = 0; j < 8; ++j)
      *(float4*)(o2 + tid * 4 + j * 2048) = gv;
  }

  // ---- stage own strip of Xb (fp32 -> bf16, swizzled)
  for (int i = 0; i < 4; ++i) {
    int e = row0 * 128 + (lane + i * 64) * 8;   // element index
    float4 f0 = *(const float4*)(xb + e);
    float4 f1 = *(const float4*)(xb + e + 4);
    unsigned p[4] = {pack2(f0.x, f0.y), pack2(f0.z, f0.w),
                     pack2(f1.x, f1.y), pack2(f1.z, f1.w)};
    *(uint4*)(t_x + sw(e >> 7, (e >> 3) & 15)) = *(const uint4*)p;
  }
  // no barrier: every wave's A-reads touch only its own staged strip

  f32x4 acc[8], accV[8];

  // ---- K = Xb @ Wk -> t_k (own strip)
  clr8(acc);
  mm_g(t_x, (const char*)(wt + 16384), row0, l15, quad, acc);
  store_strip(t_k, row0, l15, quad, acc, nullptr);

  // ---- V = Xb @ Wv -> registers (C/D layout)
  clr8(accV);
  mm_g(t_x, (const char*)(wt + 2 * 16384), row0, l15, quad, accV);

  // ---- Q = Xb @ Wq -> t_x own strip (wave-local overwrite of own Xb rows)
  clr8(acc);
  mm_g(t_x, (const char*)(wt + 0), row0, l15, quad, acc);
  store_strip(t_x, row0, l15, quad, acc, nullptr);
  __syncthreads();                          // barrier 1: K tile fully visible

  // ---- S = Q @ K^T (A = own Q strip, B = K tile)
  clr8(acc);
  mm_l(t_x, t_k, row0, l15, quad, acc);

  // ---- row softmax, no max subtraction (scores ~N(0,1) in fp32)
  float inv[4];
  const float sscale = 0.08838834764831845f;   // 1/sqrt(128)
#pragma unroll
  for (int r = 0; r < 4; ++r) {
    float sum = 0.f;
#pragma unroll
    for (int ct = 0; ct < 8; ++ct) {
      float v = __expf(acc[ct][r] * sscale);
      acc[ct][r] = v;
      sum += v;
    }
#pragma unroll
    for (int off = 8; off; off >>= 1) sum += __shfl_xor(sum, off, 64);
    inv[r] = 1.0f / sum;
  }
  store_strip(t_x, row0, l15, quad, acc, nullptr);  // P over Q (own strip)
  __syncthreads();                          // barrier 2: all waves done reading K

  // ---- publish V^T over the K tile (b64-packed), then O = P @ V^T
  storeT_strip(t_k, row0, l15, quad, accV);
  __syncthreads();                          // barrier 3: V^T visible

  clr8(acc);
  mm_l(t_x, t_k, row0, l15, quad, acc);
  store_strip(t_x, row0, l15, quad, acc, inv);  // O (normalized) over P

  // ---- H = O @ Wo
  clr8(acc);
  mm_g(t_x, (const char*)(wt + 3 * 16384), row0, l15, quad, acc);

  // ---- LayerNorm + exact GELU -> global fp32
  float gg[8], bbv[8];
#pragma unroll
  for (int ct = 0; ct < 8; ++ct) {
    gg[ct] = gamma[ct * 16 + l15];
    bbv[ct] = beta[ct * 16 + l15];
  }
#pragma unroll
  for (int r = 0; r < 4; ++r) {
    float sum = 0.f;
#pragma unroll
    for (int ct = 0; ct < 8; ++ct) sum += acc[ct][r];
#pragma unroll
    for (int off = 8; off; off >>= 1) sum += __shfl_xor(sum, off, 64);
    float mean = sum * (1.0f / 128.0f);
    float sq = 0.f;
#pragma unroll
    for (int ct = 0; ct < 8; ++ct) { float d = acc[ct][r] - mean; sq += d * d; }
#pragma unroll
    for (int off = 8; off; off >>= 1) sq += __shfl_xor(sq, off, 64);
    float rstd = rsqrtf(sq * (1.0f / 128.0f) + 1e-5f);
    int row = row0 + quad * 4 + r;
    float* op = outb + (size_t)row * 128;
#pragma unroll
    for (int ct = 0; ct < 8; ++ct) {
      float y = (acc[ct][r] - mean) * rstd * gg[ct] + bbv[ct];
      op[ct * 16 + l15] = gelu_exact(y);
    }
  }
}

extern "C" void kernel_launch(void* const* d_in, const int* in_sizes, int n_in,
                              void* d_out, int out_size, void* d_ws, size_t ws_size,
                              hipStream_t stream) {
  const float* x     = (const float*)d_in[0];
  const float* wq    = (const float*)d_in[1];
  const float* wk    = (const float*)d_in[2];
  const float* wv    = (const float*)d_in[3];
  const float* wo    = (const float*)d_in[4];
  const float* gamma = (const float*)d_in[5];
  const float* beta  = (const float*)d_in[6];
  float* out = (float*)d_out;
  bf16* wt  = (bf16*)d_ws;                  // 4 x 128 x 128 bf16 = 128 KB

  transw<<<16, 256, 0, stream>>>(wq, wk, wv, wo, wt);
  attn_ln_gelu<<<512, 512, 0, stream>>>(x, wt, gamma, beta, out);
}

// Round 4
// 174.534 us; speedup vs baseline: 1.1105x; 1.1105x over previous
//
#include <hip/hip_runtime.h>
#include <hip/hip_bf16.h>
#include <math.h>

using bf16 = __hip_bfloat16;
typedef short short8 __attribute__((ext_vector_type(8)));   // 8 bf16 = 4 VGPRs
typedef float f32x4 __attribute__((ext_vector_type(4)));    // MFMA 16x16 acc

#define MFMA16 __builtin_amdgcn_mfma_f32_16x16x32_bf16
#define S_ 8192

// swizzled LDS addressing: 128x128 bf16 tile, 256B rows of 16 x 16B chunks.
__device__ __forceinline__ int sw(int r, int chunk) {
  return r * 256 + (((chunk) ^ (r & 15)) << 4);
}

__device__ __forceinline__ float gelu_exact(float y) {
  return 0.5f * y * (1.0f + erff(y * 0.70710678118654752f));
}

__device__ __forceinline__ unsigned pack2(float a, float b) {
  unsigned ra = (unsigned)__bfloat16_as_ushort(__float2bfloat16(a));
  unsigned rb = (unsigned)__bfloat16_as_ushort(__float2bfloat16(b));
  return ra | (rb << 16);
}

// ---- weight transpose+convert: Wt[m][n][k] = bf16(W[m][k][n]); 16 blocks ----
__global__ void transw(const float* __restrict__ wq, const float* __restrict__ wk,
                       const float* __restrict__ wv, const float* __restrict__ wo,
                       bf16* __restrict__ wt) {
  __shared__ bf16 s[32 * 136];              // 32 out-rows x 128 k, pad 8
  int m = blockIdx.x >> 2, sl = blockIdx.x & 3;
  const float* W = (m == 0) ? wq : (m == 1) ? wk : (m == 2) ? wv : wo;
  for (int i = 0; i < 16; ++i) {
    int idx = threadIdx.x + i * 256;        // 0..4095
    int k = idx >> 5, nl = idx & 31;
    s[nl * 136 + k] = __float2bfloat16(W[k * 128 + sl * 32 + nl]);
  }
  __syncthreads();
  for (int i = 0; i < 2; ++i) {
    int c = threadIdx.x + i * 256;          // 0..511
    int nl = c >> 4, ch = c & 15;
    *(uint4*)(wt + m * 16384 + (sl * 32 + nl) * 128 + ch * 8) =
        *(const uint4*)(s + nl * 136 + ch * 8);
  }
}

// ---- mm helpers: 16-row strip, acc[8] --------------------------------------
__device__ __forceinline__ void clr8(f32x4 acc[8]) {
#pragma unroll
  for (int j = 0; j < 8; ++j) acc[j] = (f32x4){0.f, 0.f, 0.f, 0.f};
}

// A = own strip (LDS swizzled), B = global pre-transposed weight [n][k]
__device__ __forceinline__ void mm_g(const char* tA, const char* wB, int row0,
                                     int l15, int quad, f32x4 acc[8]) {
#pragma unroll
  for (int t = 0; t < 4; ++t) {
    short8 a = *(const short8*)(tA + sw(row0 + l15, 4 * t + quad));
#pragma unroll
    for (int ct = 0; ct < 8; ++ct) {
      short8 bb = *(const short8*)(wB + (ct * 16 + l15) * 256 + t * 64 + quad * 16);
      acc[ct] = MFMA16(a, bb, acc[ct], 0, 0, 0);
    }
  }
}

// A = own strip (LDS), B = LDS tile stored [n][k] swizzled
__device__ __forceinline__ void mm_l(const char* tA, const char* tB, int row0,
                                     int l15, int quad, f32x4 acc[8]) {
#pragma unroll
  for (int t = 0; t < 4; ++t) {
    short8 a = *(const short8*)(tA + sw(row0 + l15, 4 * t + quad));
#pragma unroll
    for (int ct = 0; ct < 8; ++ct) {
      short8 bb = *(const short8*)(tB + sw(ct * 16 + l15, 4 * t + quad));
      acc[ct] = MFMA16(a, bb, acc[ct], 0, 0, 0);
    }
  }
}

// C/D strip -> row-major swizzled tile (own 16 rows), optional per-row scale
__device__ __forceinline__ void store_strip(char* tile, int row0, int l15, int quad,
                                            const f32x4 acc[8], const float* rs) {
#pragma unroll
  for (int ct = 0; ct < 8; ++ct) {
    int col = ct * 16 + l15;
#pragma unroll
    for (int r = 0; r < 4; ++r) {
      int row = row0 + quad * 4 + r;
      float v = acc[ct][r];
      if (rs) v *= rs[r];
      *(bf16*)(tile + sw(row, col >> 3) + (col & 7) * 2) = __float2bfloat16(v);
    }
  }
}

// packed bf16 V strip -> transposed tile [col][row], ds_write_b64
__device__ __forceinline__ void storeT_packed(char* tile, int row0, int l15,
                                              int quad, const unsigned* pV) {
  int seq = row0 + quad * 4;                // 4-aligned
#pragma unroll
  for (int ct = 0; ct < 8; ++ct) {
    int d = ct * 16 + l15;
    unsigned p[2] = {pV[2 * ct], pV[2 * ct + 1]};
    *(uint2*)(tile + sw(d, seq >> 3) + (seq & 7) * 2) = *(const uint2*)p;
  }
}

// ---- main: per-block attention + LN + GELU + second-half fill ---------------
__global__ __launch_bounds__(512, 2) void attn_ln_gelu(
    const float* __restrict__ x, const bf16* __restrict__ wt,
    const float* __restrict__ gamma, const float* __restrict__ beta,
    float* __restrict__ out) {
  __shared__ uint4 ldsbuf[4096];            // 64 KB: 2 tiles
  char* t_x = (char*)ldsbuf;                // Xb -> Q -> P -> O (own strips)
  char* t_k = t_x + 32768;                  // K -> V^T

  const int tid = threadIdx.x;
  const int wave = tid >> 6, lane = tid & 63;
  const int l15 = lane & 15, quad = lane >> 4;
  const int row0 = wave << 4;               // own 16-row strip
  const int b = blockIdx.x >> 6, blk = blockIdx.x & 63;
  const float* xb = x + ((size_t)b * S_ + (size_t)blk * 128) * 128;
  float* outb = out + ((size_t)b * 2 * S_ + (size_t)blk * 128) * 128;

  // ---- second-half fill: out2 = gelu(beta[d]) broadcast
  {
    float* o2 = out + ((size_t)b * 2 * S_ + (size_t)(S_ + blk * 128)) * 128;
    int c0 = (tid * 4) & 127;
    float4 bv = *(const float4*)(beta + c0);
    float4 gv;
    gv.x = gelu_exact(bv.x); gv.y = gelu_exact(bv.y);
    gv.z = gelu_exact(bv.z); gv.w = gelu_exact(bv.w);
#pragma unroll
    for (int j = 0; j < 8; ++j)
      *(float4*)(o2 + tid * 4 + j * 2048) = gv;
  }

  // ---- stage own strip of Xb (fp32 -> bf16, swizzled)
  for (int i = 0; i < 4; ++i) {
    int e = row0 * 128 + (lane + i * 64) * 8;   // element index
    float4 f0 = *(const float4*)(xb + e);
    float4 f1 = *(const float4*)(xb + e + 4);
    unsigned p[4] = {pack2(f0.x, f0.y), pack2(f0.z, f0.w),
                     pack2(f1.x, f1.y), pack2(f1.z, f1.w)};
    *(uint4*)(t_x + sw(e >> 7, (e >> 3) & 15)) = *(const uint4*)p;
  }
  // no barrier: every wave's A-reads touch only its own staged strip

  f32x4 acc[8];
  unsigned pV[16];                          // V strip packed bf16 (16 VGPRs)

  // ---- K = Xb @ Wk -> t_k (own strip)
  clr8(acc);
  mm_g(t_x, (const char*)(wt + 16384), row0, l15, quad, acc);
  store_strip(t_k, row0, l15, quad, acc, nullptr);

  // ---- V = Xb @ Wv -> packed registers
  clr8(acc);
  mm_g(t_x, (const char*)(wt + 2 * 16384), row0, l15, quad, acc);
#pragma unroll
  for (int ct = 0; ct < 8; ++ct) {
    pV[2 * ct]     = pack2(acc[ct][0], acc[ct][1]);
    pV[2 * ct + 1] = pack2(acc[ct][2], acc[ct][3]);
  }

  // ---- Q = Xb @ Wq -> t_x own strip (wave-local overwrite of own Xb rows)
  clr8(acc);
  mm_g(t_x, (const char*)(wt + 0), row0, l15, quad, acc);
  store_strip(t_x, row0, l15, quad, acc, nullptr);
  __syncthreads();                          // barrier 1: K tile fully visible

  // ---- S = Q @ K^T (A = own Q strip, B = K tile)
  clr8(acc);
  mm_l(t_x, t_k, row0, l15, quad, acc);

  // ---- row softmax, no max subtraction (scores ~N(0,1) in fp32)
  float inv[4];
  const float sscale = 0.08838834764831845f;   // 1/sqrt(128)
#pragma unroll
  for (int r = 0; r < 4; ++r) {
    float sum = 0.f;
#pragma unroll
    for (int ct = 0; ct < 8; ++ct) {
      float v = __expf(acc[ct][r] * sscale);
      acc[ct][r] = v;
      sum += v;
    }
#pragma unroll
    for (int off = 8; off; off >>= 1) sum += __shfl_xor(sum, off, 64);
    inv[r] = 1.0f / sum;
  }
  store_strip(t_x, row0, l15, quad, acc, nullptr);  // P over Q (own strip)
  __syncthreads();                          // barrier 2: all waves done reading K

  // ---- publish V^T over the K tile, then O = P @ V^T
  storeT_packed(t_k, row0, l15, quad, pV);
  __syncthreads();                          // barrier 3: V^T visible

  clr8(acc);
  mm_l(t_x, t_k, row0, l15, quad, acc);
  store_strip(t_x, row0, l15, quad, acc, inv);  // O (normalized) over P

  // ---- H = O @ Wo
  clr8(acc);
  mm_g(t_x, (const char*)(wt + 3 * 16384), row0, l15, quad, acc);

  // ---- LayerNorm + exact GELU -> global fp32
  float gg[8], bbv[8];
#pragma unroll
  for (int ct = 0; ct < 8; ++ct) {
    gg[ct] = gamma[ct * 16 + l15];
    bbv[ct] = beta[ct * 16 + l15];
  }
#pragma unroll
  for (int r = 0; r < 4; ++r) {
    float sum = 0.f;
#pragma unroll
    for (int ct = 0; ct < 8; ++ct) sum += acc[ct][r];
#pragma unroll
    for (int off = 8; off; off >>= 1) sum += __shfl_xor(sum, off, 64);
    float mean = sum * (1.0f / 128.0f);
    float sq = 0.f;
#pragma unroll
    for (int ct = 0; ct < 8; ++ct) { float d = acc[ct][r] - mean; sq += d * d; }
#pragma unroll
    for (int off = 8; off; off >>= 1) sq += __shfl_xor(sq, off, 64);
    float rstd = rsqrtf(sq * (1.0f / 128.0f) + 1e-5f);
    int row = row0 + quad * 4 + r;
    float* op = outb + (size_t)row * 128;
#pragma unroll
    for (int ct = 0; ct < 8; ++ct) {
      float y = (acc[ct][r] - mean) * rstd * gg[ct] + bbv[ct];
      op[ct * 16 + l15] = gelu_exact(y);
    }
  }
}

extern "C" void kernel_launch(void* const* d_in, const int* in_sizes, int n_in,
                              void* d_out, int out_size, void* d_ws, size_t ws_size,
                              hipStream_t stream) {
  const float* x     = (const float*)d_in[0];
  const float* wq    = (const float*)d_in[1];
  const float* wk    = (const float*)d_in[2];
  const float* wv    = (const float*)d_in[3];
  const float* wo    = (const float*)d_in[4];
  const float* gamma = (const float*)d_in[5];
  const float* beta  = (const float*)d_in[6];
  float* out = (float*)d_out;
  bf16* wt  = (bf16*)d_ws;                  // 4 x 128 x 128 bf16 = 128 KB

  transw<<<16, 256, 0, stream>>>(wq, wk, wv, wo, wt);
  attn_ln_gelu<<<512, 512, 0, stream>>>(x, wt, gamma, beta, out);
}